// Round 17
// baseline (4800.525 us; speedup 1.0000x reference)
//
#include <hip/hip_runtime.h>
#include <math.h>

#define B_  64
#define H_  64
#define W_  64
#define HW  4096   // H_*W_
#define NPIX 262144.0f  // B_*HW

typedef _Float16 f16x8 __attribute__((ext_vector_type(8)));
typedef float    f32x4 __attribute__((ext_vector_type(4)));
typedef float    f32x2 __attribute__((ext_vector_type(2), aligned(4)));

// ---------------------------------------------------------------------------
// Weight pack into MFMA B-fragment layout.
// dst[((ch*NT+nt)*64 + l)*8 + j] = w(o = nt*16+(l&15), K = ch*32+(l>>4)*8+j).
// K-order: conv (CG==0): K = ci*9 + t  (w flat = o*KK + K).
//          deform:       K = g*(9*CG) + k*CG + c (src = o*KK + (g*CG+c)*9+k).
// ---------------------------------------------------------------------------
__global__ __launch_bounds__(256) void wfrag_k(
    const float* __restrict__ w, _Float16* __restrict__ dst,
    int O, int KK, int NT, int NCH, int CG)
{
    const int i = blockIdx.x * 256 + threadIdx.x;
    const int total = NCH * NT * 64 * 8;
    if (i >= total) return;
    const int j  = i & 7;
    const int l  = (i >> 3) & 63;
    const int nt = (i >> 9) % NT;
    const int ch = (i >> 9) / NT;
    const int K  = ch * 32 + (l >> 4) * 8 + j;
    const int o  = nt * 16 + (l & 15);
    float v = 0.f;
    if (K < KK && o < O) {
        int src;
        if (CG == 0) {
            src = o * KK + K;
        } else {
            const int g = K / (9 * CG);
            const int r = K - g * (9 * CG);
            const int k = r / CG;
            const int c = r - k * CG;
            src = o * KK + (g * CG + c) * 9 + k;
        }
        v = w[src];
    }
    dst[i] = (_Float16)v;
}

// ---------------------------------------------------------------------------
// BN stats helpers (conv1 uses block-level version).
// ---------------------------------------------------------------------------
template<int CT>
__device__ __forceinline__ void stats_accum(
    const float* res, float* sacc, float* ls, int tid)
{
    if (tid < 2 * CT) ls[tid] = 0.f;
    __syncthreads();
#pragma unroll
    for (int o = 0; o < CT; ++o) {
        float s = res[o], s2 = res[o] * res[o];
        for (int off = 32; off; off >>= 1) {
            s  += __shfl_down(s,  off);
            s2 += __shfl_down(s2, off);
        }
        if ((tid & 63) == 0) {
            atomicAdd(&ls[2 * o],     s);
            atomicAdd(&ls[2 * o + 1], s2);
        }
    }
    __syncthreads();
    if (tid < 2 * CT) atomicAdd(&sacc[tid], ls[tid]);
}

template<int C>
__global__ __launch_bounds__(64) void bn_fin_k(
    const float* __restrict__ sacc, float* __restrict__ st)
{
    const int t = threadIdx.x;
    if (t < C) {
        const float mean = sacc[2 * t] / NPIX;
        const float var  = sacc[2 * t + 1] / NPIX - mean * mean;
        st[t]     = mean;
        st[C + t] = rsqrtf(var + 1e-5f);
    }
}

// ---------------------------------------------------------------------------
// conv1: 3x3 conv (3->8) + ReLU, NCHW, fused stats (small; scalar fp32).
// ---------------------------------------------------------------------------
__global__ __launch_bounds__(256) void conv1_k(
    const float* __restrict__ x, const float* __restrict__ w,
    float* __restrict__ out, float* __restrict__ sacc)
{
    const int tid = threadIdx.x;
    const int pix = blockIdx.x * 256 + tid;
    const int b   = blockIdx.y;
    const int h   = pix >> 6, ww = pix & 63;

    float acc[8];
#pragma unroll
    for (int o = 0; o < 8; ++o) acc[o] = 0.f;

#pragma unroll
    for (int ci = 0; ci < 3; ++ci) {
        const float* xp = x + ((size_t)b * 3 + ci) * HW;
#pragma unroll
        for (int t = 0; t < 9; ++t) {
            const int yy = h + t / 3 - 1, xx = ww + t % 3 - 1;
            const bool ok = (yy >= 0) && (yy < 64) && (xx >= 0) && (xx < 64);
            const float xv = ok ? xp[min(max(yy,0),63) * 64 + min(max(xx,0),63)] : 0.f;
#pragma unroll
            for (int o = 0; o < 8; ++o)
                acc[o] = fmaf(w[o * 27 + ci * 9 + t], xv, acc[o]);
        }
    }

    float res[8];
    float* ob = out + (size_t)b * 8 * HW + pix;
#pragma unroll
    for (int o = 0; o < 8; ++o) {
        res[o] = fmaxf(acc[o], 0.f);
        ob[(size_t)o * HW] = res[o];
    }

    __shared__ float ls[16];
    stats_accum<8>(res, sacc, ls, tid);
}

// ---------------------------------------------------------------------------
// Unified MFMA kernel — R12 barrier structure, re-tiled for concurrency:
//   * 128 PIXELS per block, 256 threads (4 waves). Grid 2048 -> 8 blocks/CU
//     possible (LDS ~19.4 KB); acc[2][NT] (32 VGPR) -> more waves resident.
//   * SPLIT-K produce: thread t gathers pixel (t&127), K-half (t>>7) = 16
//     values -> per-thread gather chain halves; all threads busy. K-half via
//     compile-time KH loop (indices stay static).
//   * Wave wv's MFMA reads rows wv*32 + mt*16 + (lane&15) (cross-wave LDS,
//     barriers as R12). f32x2 corner pairs (R14-proven).
// ---------------------------------------------------------------------------
template<int KK, int O, int NT, int CG, int CIN, bool RELU, bool STATS>
__global__ __launch_bounds__(256) __attribute__((amdgpu_waves_per_eu(1, 4)))
void mfconv_k(
    const float* __restrict__ x, const float* __restrict__ om,
    const _Float16* __restrict__ wf, const float* __restrict__ bias,
    const float* __restrict__ st, const float* __restrict__ gg,
    const float* __restrict__ bb,
    float* __restrict__ out, float* __restrict__ sacc)
{
    constexpr int NCH = (KK + 31) / 32;
    const int tid   = threadIdx.x;
    const int lane  = tid & 63;
    const int wv    = tid >> 6;
    const int p     = tid & 127;           // produced pixel within block
    const int khalf = tid >> 7;            // 0 or 1: K-half of the chunk
    const int pix0  = blockIdx.x * 128;
    const int pix   = pix0 + p;
    const int b     = blockIdx.y;
    const int h     = pix >> 6, ww = pix & 63;

    __shared__ __align__(16) _Float16 vlds[128][40];   // 32 f16 + pad (80B rows)
    __shared__ float tlds[128][17];
    __shared__ float lsa[CIN], lsc[CIN];

    if (tid < CIN) {
        const float mean = st[tid], rstd = st[CIN + tid];
        lsa[tid] = gg[tid] * rstd;
        lsc[tid] = bb[tid] - gg[tid] * mean * rstd;
    }

    // dense-conv tap tables (statically indexed only)
    int  tpix[9]; bool tok[9];
    if (CG == 0) {
#pragma unroll
        for (int t = 0; t < 9; ++t) {
            const int yy = h + t / 3 - 1, xx = ww + t % 3 - 1;
            tok[t]  = (yy >= 0) && (yy < 64) && (xx >= 0) && (xx < 64);
            tpix[t] = min(max(yy, 0), 63) * 64 + min(max(xx, 0), 63);
        }
    }

    const float* xb  = x + (size_t)b * CIN * HW;
    const float* omb = om + (size_t)b * 54 * HW + pix;   // unused for CG==0
    __syncthreads();

    f32x4 acc[2][NT];
#pragma unroll
    for (int mt = 0; mt < 2; ++mt)
#pragma unroll
        for (int nt = 0; nt < NT; ++nt)
            acc[mt][nt] = (f32x4){0.f, 0.f, 0.f, 0.f};

    // deform tap state (recomputed at c==0 or at thread's first element)
    float tw0 = 0.f, tw1 = 0.f, tw2 = 0.f, tw3 = 0.f, twsum = 0.f;
    int   ibase = 0, idx = 0, idy = 0;

#pragma unroll
    for (int ch = 0; ch < NCH; ++ch) {
        // ---- produce this thread's 16 A-values (2 x ds_write_b128)
#pragma unroll
        for (int KH = 0; KH < 2; ++KH) {
            if (khalf == KH) {
#pragma unroll
                for (int q2 = 0; q2 < 2; ++q2) {
                    f16x8 pk;
#pragma unroll
                    for (int jj = 0; jj < 8; ++jj) {
                        const int j  = KH * 16 + q2 * 8 + jj;
                        const int kk = ch * 32 + j;
                        float v = 0.f;
                        if (kk < KK) {
                            if (CG == 0) {
                                const int ci = kk / 9, t = kk - (kk / 9) * 9;
                                const float xval = xb[(size_t)ci * HW + tpix[t]];
                                v = tok[t] ? fmaf(lsa[ci], xval, lsc[ci]) : 0.f;
                            } else {
                                const int tp = kk / CG;          // g*9 + k
                                const int c  = kk - tp * CG;
                                const int g  = tp / 9, k = tp - (tp / 9) * 9;
                                if (c == 0 || (q2 == 0 && jj == 0)) {
                                    const float offy = omb[(size_t)tp * HW];
                                    const float offx = omb[(size_t)(18 + tp) * HW];
                                    const float mraw = omb[(size_t)(36 + tp) * HW];
                                    const float msk  = 1.f / (1.f + __expf(-mraw));
                                    const float py = (float)(h + k / 3 - 1) + offy;
                                    const float px = (float)(ww + k % 3 - 1) + offx;
                                    const float y0f = floorf(py), x0f = floorf(px);
                                    const float lyf = py - y0f, lxf = px - x0f;
                                    const int y0 = (int)y0f, x0 = (int)x0f;
                                    const int y1 = y0 + 1,  x1 = x0 + 1;
                                    const bool y0ok = (y0 >= 0) && (y0 < 64);
                                    const bool y1ok = (y1 >= 0) && (y1 < 64);
                                    const bool x0ok = (x0 >= 0) && (x0 < 64);
                                    const bool x1ok = (x1 >= 0) && (x1 < 64);
                                    tw0 = (1.f-lyf)*(1.f-lxf)*msk; if (!(y0ok&&x0ok)) tw0 = 0.f;
                                    tw1 = (1.f-lyf)*lxf      *msk; if (!(y0ok&&x1ok)) tw1 = 0.f;
                                    tw2 = lyf*(1.f-lxf)      *msk; if (!(y1ok&&x0ok)) tw2 = 0.f;
                                    tw3 = lyf*lxf            *msk; if (!(y1ok&&x1ok)) tw3 = 0.f;
                                    twsum = tw0 + tw1 + tw2 + tw3;
                                    ibase = min(max(y0,0),63) * 64 + min(max(x0,0),63);
                                    idx   = (min(max(x1,0),63) - min(max(x0,0),63));
                                    idy   = (min(max(y1,0),63) - min(max(y0,0),63)) * 64;
                                }
                                const int chn = g * CG + c;
                                const float* xp = xb + (size_t)chn * HW + ibase;
                                const f32x2 r0 = *(const f32x2*)xp;          // [x0, x0+1]
                                const f32x2 r1 = *(const f32x2*)(xp + idy);  // @y1
                                const float v00 = r0.x, v01 = idx ? r0.y : r0.x;
                                const float v10 = r1.x, v11 = idx ? r1.y : r1.x;
                                const float gath = tw0*v00 + tw1*v01 + tw2*v10 + tw3*v11;
                                v = fmaf(lsa[chn], gath, lsc[chn] * twsum);
                            }
                        }
                        pk[jj] = (_Float16)v;
                    }
                    *(f16x8*)&vlds[p][KH * 16 + q2 * 8] = pk;
                }
            }
        }
        __syncthreads();

        // ---- MFMA: A from LDS (cross-wave), B from precomputed fragments
        f16x8 bf[NT];
#pragma unroll
        for (int nt = 0; nt < NT; ++nt)
            bf[nt] = *(const f16x8*)&wf[((size_t)(ch * NT + nt) * 64 + lane) * 8];
#pragma unroll
        for (int mt = 0; mt < 2; ++mt) {
            const int pr = wv * 32 + mt * 16 + (lane & 15);
            const f16x8 af = *(const f16x8*)&vlds[pr][(lane >> 4) * 8];
#pragma unroll
            for (int nt = 0; nt < NT; ++nt)
                acc[mt][nt] = __builtin_amdgcn_mfma_f32_16x16x32_f16(
                    af, bf[nt], acc[mt][nt], 0, 0, 0);
        }
        __syncthreads();
    }

    // ---- epilogue: LDS transpose -> coalesced NCHW writes (+bias/ReLU/stats)
    float* obase = out + (size_t)b * O * HW + pix0;
#pragma unroll
    for (int nt = 0; nt < NT; ++nt) {
#pragma unroll
        for (int mt = 0; mt < 2; ++mt)
#pragma unroll
            for (int r = 0; r < 4; ++r)
                tlds[wv * 32 + mt * 16 + ((lane >> 4) << 2) + r][lane & 15] =
                    acc[mt][nt][r];
        __syncthreads();

        float res[16];
#pragma unroll
        for (int oi = 0; oi < 16; ++oi) {
            const int o = nt * 16 + oi;
            float v = 0.f;
            if (o < O && tid < 128) {
                v = tlds[tid][oi] + bias[o];
                if (RELU) v = fmaxf(v, 0.f);
                obase[(size_t)o * HW + tid] = v;
            }
            res[oi] = v;
        }
        if (STATS) {
#pragma unroll
            for (int oi = 0; oi < 16; ++oi) {
                const int o = nt * 16 + oi;
                if (o < O) {
                    float s = res[oi], s2 = res[oi] * res[oi];
                    for (int off = 32; off; off >>= 1) {
                        s  += __shfl_down(s,  off);
                        s2 += __shfl_down(s2, off);
                    }
                    if (lane == 0 && wv < 2) {
                        atomicAdd(&sacc[2 * o],     s);
                        atomicAdd(&sacc[2 * o + 1], s2);
                    }
                }
            }
        }
        __syncthreads();
    }
}

// ---------------------------------------------------------------------------
// BN apply in place on em (NCHW 64ch): 4,194,304 float4 -> 16384 blocks.
// ---------------------------------------------------------------------------
__global__ __launch_bounds__(256) void bn_apply4_k(
    float* __restrict__ y, const float* __restrict__ st,
    const float* __restrict__ gg, const float* __restrict__ bb)
{
    const size_t i4 = (size_t)blockIdx.x * 256 + threadIdx.x;
    const int c = (int)((i4 >> 10) & 63);
    const float m = st[c], r = st[64 + c];
    const float a = gg[c] * r, cc = bb[c] - gg[c] * m * r;
    float4 v = ((float4*)y)[i4];
    v.x = a*v.x + cc; v.y = a*v.y + cc; v.z = a*v.z + cc; v.w = a*v.w + cc;
    ((float4*)y)[i4] = v;
}

__global__ __launch_bounds__(256) void pool_k(
    const float* __restrict__ em, float* __restrict__ pooled)
{
    const int b = blockIdx.x, c = blockIdx.y, t = threadIdx.x;
    const int q = t >> 6, l = t & 63;
    const float* p = em + ((size_t)b * 64 + c) * HW + (q >> 1) * 32 * W_ + (q & 1) * 32;
    float s = 0.f;
    for (int i = l; i < 1024; i += 64) {
        const int yy = i >> 5, xx = i & 31;
        s += p[yy * W_ + xx];
    }
    for (int off = 32; off; off >>= 1) s += __shfl_down(s, off);
    if (l == 0) pooled[b * 256 + c * 4 + q] = s * (1.f / 1024.f);
}

__global__ __launch_bounds__(64) void fc_k(
    const float* __restrict__ pooled, const float* __restrict__ fcw,
    const float* __restrict__ fcb, float* __restrict__ out)
{
    const int b = blockIdx.x, t = threadIdx.x;
    __shared__ float logits[10];
    if (t < 10) {
        float l = fcb[t];
        const float* p = pooled + b * 256;
        for (int j = 0; j < 256; ++j) l += fcw[t * 256 + j] * p[j];
        logits[t] = l;
    }
    __syncthreads();
    if (t == 0) {
        float mx = logits[0];
        for (int i = 1; i < 10; ++i) mx = fmaxf(mx, logits[i]);
        float e[10]; float sum = 0.f;
        for (int i = 0; i < 10; ++i) { e[i] = __expf(logits[i] - mx); sum += e[i]; }
        const float inv = 1.f / sum;
        for (int i = 0; i < 10; ++i) out[b * 10 + i] = e[i] * inv;
    }
}

// ---------------------------------------------------------------------------
extern "C" void kernel_launch(void* const* d_in, const int* in_sizes, int n_in,
                              void* d_out, int out_size, void* d_ws, size_t ws_size,
                              hipStream_t stream)
{
    const float* x       = (const float*)d_in[0];
    const float* conv1_w = (const float*)d_in[1];
    const float* bn1_g   = (const float*)d_in[2];
    const float* bn1_b   = (const float*)d_in[3];
    const float* conv2_w = (const float*)d_in[4];
    const float* conv2_b = (const float*)d_in[5];
    const float* bn2_g   = (const float*)d_in[6];
    const float* bn2_b   = (const float*)d_in[7];
    const float* off1_w  = (const float*)d_in[8];
    const float* off1_b  = (const float*)d_in[9];
    const float* d1_w    = (const float*)d_in[10];
    const float* d1_b    = (const float*)d_in[11];
    const float* bn3_g   = (const float*)d_in[12];
    const float* bn3_b   = (const float*)d_in[13];
    const float* off2_w  = (const float*)d_in[14];
    const float* off2_b  = (const float*)d_in[15];
    const float* d2_w    = (const float*)d_in[16];
    const float* d2_b    = (const float*)d_in[17];
    const float* bn4_g   = (const float*)d_in[18];
    const float* bn4_b   = (const float*)d_in[19];
    const float* fc_w    = (const float*)d_in[20];
    const float* fc_b    = (const float*)d_in[21];

    // Workspace (floats), all NCHW. ~119.7 MB.
    float* ws = (float*)d_ws;
    float* Bb = ws;                    // [B][20][HW]  5,242,880
    float* D  = ws + 5242880;          // [B][40][HW] 10,485,760
    float* C  = ws + 15728640;         // om [B][54][HW] 14,155,776
    float* A  = C;                     // [B][8][HW] (aliases C; dead before off1)
    float* sm = ws + 29884416;
    float* s1 = sm,        *s2 = sm + 16,  *s3 = sm + 56,  *s4 = sm + 136; // sums (264)
    float* st1 = sm + 264, *st2 = sm + 280, *st3 = sm + 320, *st4 = sm + 400;
    float* pooled = sm + 528;          // 16384 (end 16912)
    // MFMA weight fragments (f16)
    _Float16* c2F = (_Float16*)(sm + 16912);  //  3,072 f16
    _Float16* o1F = (_Float16*)(sm + 18448);  // 12,288 f16
    _Float16* o2F = (_Float16*)(sm + 24592);  // 24,576 f16
    _Float16* d1F = (_Float16*)(sm + 36880);  //  9,216 f16
    _Float16* d2F = (_Float16*)(sm + 41488);  // 24,576 f16 (end 53776)

    float* outp = (float*)d_out;
    float* em   = outp + 640;          // NCHW [64][64][64][64]

    const dim3 blk(256);
    const dim3 gmf(32, B_);            // 128-px blocks, 256 thr: 2048 blocks

    (void)hipMemsetAsync(sm, 0, 264 * sizeof(float), stream);

    // pack weights into fragment layout:        w        dst   O   KK  NT NCH CG
    wfrag_k<<<(3072  + 255)/256, blk, 0, stream>>>(conv2_w, c2F, 20,  72, 2,  3,  0);
    wfrag_k<<<(12288 + 255)/256, blk, 0, stream>>>(off1_w,  o1F, 54, 180, 4,  6,  0);
    wfrag_k<<<(24576 + 255)/256, blk, 0, stream>>>(off2_w,  o2F, 54, 360, 4, 12,  0);
    wfrag_k<<<(9216  + 255)/256, blk, 0, stream>>>(d1_w,    d1F, 40, 180, 3,  6, 10);
    wfrag_k<<<(24576 + 255)/256, blk, 0, stream>>>(d2_w,    d2F, 64, 360, 4, 12, 20);

    // layer 1: conv(3->8)+relu -> A + stats1
    conv1_k<<<dim3(16, B_), blk, 0, stream>>>(x, conv1_w, A, s1);
    bn_fin_k<8><<<1, 64, 0, stream>>>(s1, st1);

    // layer 2: conv(8->20)+bias+relu (BN1 inline) -> Bb + stats2
    mfconv_k<72, 20, 2, 0, 8, true, true><<<gmf, blk, 0, stream>>>(
        A, nullptr, c2F, conv2_b, st1, bn1_g, bn1_b, Bb, s2);
    bn_fin_k<20><<<1, 64, 0, stream>>>(s2, st2);

    // deform block 1: off-conv(20->54, BN2 inline) -> C; deform(20->40) -> D
    mfconv_k<180, 54, 4, 0, 20, false, false><<<gmf, blk, 0, stream>>>(
        Bb, nullptr, o1F, off1_b, st2, bn2_g, bn2_b, C, nullptr);
    mfconv_k<180, 40, 3, 10, 20, true, true><<<gmf, blk, 0, stream>>>(
        Bb, C, d1F, d1_b, st2, bn2_g, bn2_b, D, s3);
    bn_fin_k<40><<<1, 64, 0, stream>>>(s3, st3);

    // deform block 2: off-conv(40->54, BN3 inline) -> C; deform(40->64) -> em
    mfconv_k<360, 54, 4, 0, 40, false, false><<<gmf, blk, 0, stream>>>(
        D, nullptr, o2F, off2_b, st3, bn3_g, bn3_b, C, nullptr);
    mfconv_k<360, 64, 4, 20, 40, true, true><<<gmf, blk, 0, stream>>>(
        D, C, d2F, d2_b, st3, bn3_g, bn3_b, em, s4);
    bn_fin_k<64><<<1, 64, 0, stream>>>(s4, st4);

    // layer-4 BN in place on em
    bn_apply4_k<<<16384, blk, 0, stream>>>(em, st4, bn4_g, bn4_b);

    // head
    pool_k<<<dim3(B_, 64), blk, 0, stream>>>(em, pooled);
    fc_k<<<B_, 64, 0, stream>>>(pooled, fc_w, fc_b, outp);
}

// Round 18
// 810.006 us; speedup vs baseline: 5.9265x; 5.9265x over previous
//
#include <hip/hip_runtime.h>
#include <math.h>

#define B_  64
#define H_  64
#define W_  64
#define HW  4096   // H_*W_
#define NPIX 262144.0f  // B_*HW

typedef _Float16 f16x8 __attribute__((ext_vector_type(8)));
typedef float    f32x4 __attribute__((ext_vector_type(4)));
typedef float    f32x2 __attribute__((ext_vector_type(2), aligned(4)));

// ---------------------------------------------------------------------------
// Weight pack into MFMA B-fragment layout.
// dst[((ch*NT+nt)*64 + l)*8 + j] = w(o = nt*16+(l&15), K = ch*32+(l>>4)*8+j).
// K-order: conv (CG==0): K = ci*9 + t  (w flat = o*KK + K).
//          deform:       K = g*(9*CG) + k*CG + c (src = o*KK + (g*CG+c)*9+k).
// ---------------------------------------------------------------------------
__global__ __launch_bounds__(256) void wfrag_k(
    const float* __restrict__ w, _Float16* __restrict__ dst,
    int O, int KK, int NT, int NCH, int CG)
{
    const int i = blockIdx.x * 256 + threadIdx.x;
    const int total = NCH * NT * 64 * 8;
    if (i >= total) return;
    const int j  = i & 7;
    const int l  = (i >> 3) & 63;
    const int nt = (i >> 9) % NT;
    const int ch = (i >> 9) / NT;
    const int K  = ch * 32 + (l >> 4) * 8 + j;
    const int o  = nt * 16 + (l & 15);
    float v = 0.f;
    if (K < KK && o < O) {
        int src;
        if (CG == 0) {
            src = o * KK + K;
        } else {
            const int g = K / (9 * CG);
            const int r = K - g * (9 * CG);
            const int k = r / CG;
            const int c = r - k * CG;
            src = o * KK + (g * CG + c) * 9 + k;
        }
        v = w[src];
    }
    dst[i] = (_Float16)v;
}

// ---------------------------------------------------------------------------
// BN stats helpers (conv1 uses block-level version).
// ---------------------------------------------------------------------------
template<int CT>
__device__ __forceinline__ void stats_accum(
    const float* res, float* sacc, float* ls, int tid)
{
    if (tid < 2 * CT) ls[tid] = 0.f;
    __syncthreads();
#pragma unroll
    for (int o = 0; o < CT; ++o) {
        float s = res[o], s2 = res[o] * res[o];
        for (int off = 32; off; off >>= 1) {
            s  += __shfl_down(s,  off);
            s2 += __shfl_down(s2, off);
        }
        if ((tid & 63) == 0) {
            atomicAdd(&ls[2 * o],     s);
            atomicAdd(&ls[2 * o + 1], s2);
        }
    }
    __syncthreads();
    if (tid < 2 * CT) atomicAdd(&sacc[tid], ls[tid]);
}

template<int C>
__global__ __launch_bounds__(64) void bn_fin_k(
    const float* __restrict__ sacc, float* __restrict__ st)
{
    const int t = threadIdx.x;
    if (t < C) {
        const float mean = sacc[2 * t] / NPIX;
        const float var  = sacc[2 * t + 1] / NPIX - mean * mean;
        st[t]     = mean;
        st[C + t] = rsqrtf(var + 1e-5f);
    }
}

// ---------------------------------------------------------------------------
// conv1: 3x3 conv (3->8) + ReLU, NCHW, fused stats (small; scalar fp32).
// ---------------------------------------------------------------------------
__global__ __launch_bounds__(256) void conv1_k(
    const float* __restrict__ x, const float* __restrict__ w,
    float* __restrict__ out, float* __restrict__ sacc)
{
    const int tid = threadIdx.x;
    const int pix = blockIdx.x * 256 + tid;
    const int b   = blockIdx.y;
    const int h   = pix >> 6, ww = pix & 63;

    float acc[8];
#pragma unroll
    for (int o = 0; o < 8; ++o) acc[o] = 0.f;

#pragma unroll
    for (int ci = 0; ci < 3; ++ci) {
        const float* xp = x + ((size_t)b * 3 + ci) * HW;
#pragma unroll
        for (int t = 0; t < 9; ++t) {
            const int yy = h + t / 3 - 1, xx = ww + t % 3 - 1;
            const bool ok = (yy >= 0) && (yy < 64) && (xx >= 0) && (xx < 64);
            const float xv = ok ? xp[min(max(yy,0),63) * 64 + min(max(xx,0),63)] : 0.f;
#pragma unroll
            for (int o = 0; o < 8; ++o)
                acc[o] = fmaf(w[o * 27 + ci * 9 + t], xv, acc[o]);
        }
    }

    float res[8];
    float* ob = out + (size_t)b * 8 * HW + pix;
#pragma unroll
    for (int o = 0; o < 8; ++o) {
        res[o] = fmaxf(acc[o], 0.f);
        ob[(size_t)o * HW] = res[o];
    }

    __shared__ float ls[16];
    stats_accum<8>(res, sacc, ls, tid);
}

// ---------------------------------------------------------------------------
// Unified MFMA kernel — EXACT round-12 control flow (proven no-spill, 816us),
// resource change only:
//   * vlds rows 40->36 f16 (72B rows; bank stride 18 still conflict-spread)
//   * tlds (epilogue transpose, f32 [256][18]) OVERLAYS vlds via union —
//     never live simultaneously (K-loop's final barrier separates them).
//   LDS 38.4 -> ~19 KB: occupancy cap moves from LDS-bound 16 waves/CU to
//   VGPR-bound ~20 waves/CU, 5 barrier-independent blocks/CU.
//   f32x2 corner-pair gather (R14/R16-proven identical numerics).
// ---------------------------------------------------------------------------
template<int KK, int O, int NT, int CG, int CIN, bool RELU, bool STATS>
__global__ __launch_bounds__(256) void mfconv_k(
    const float* __restrict__ x, const float* __restrict__ om,
    const _Float16* __restrict__ wf, const float* __restrict__ bias,
    const float* __restrict__ st, const float* __restrict__ gg,
    const float* __restrict__ bb,
    float* __restrict__ out, float* __restrict__ sacc)
{
    constexpr int NCH = (KK + 31) / 32;
    const int tid  = threadIdx.x;
    const int lane = tid & 63;
    const int wv   = tid >> 6;
    const int pix  = blockIdx.x * 256 + tid;
    const int b    = blockIdx.y;
    const int h    = pix >> 6, ww = pix & 63;

    // union: vlds f16[256][36] (72B rows) overlaid with tlds f32[256][18]
    __shared__ __align__(16) unsigned char usmem[256 * 72];
    _Float16* vlds = (_Float16*)usmem;
    float*    tlds = (float*)usmem;
    __shared__ float lsa[CIN], lsc[CIN];
    __shared__ float ls[32];

    if (tid < CIN) {
        const float mean = st[tid], rstd = st[CIN + tid];
        lsa[tid] = gg[tid] * rstd;
        lsc[tid] = bb[tid] - gg[tid] * mean * rstd;
    }

    // dense-conv tap tables (statically indexed only)
    int  tpix[9]; bool tok[9];
    if (CG == 0) {
#pragma unroll
        for (int t = 0; t < 9; ++t) {
            const int yy = h + t / 3 - 1, xx = ww + t % 3 - 1;
            tok[t]  = (yy >= 0) && (yy < 64) && (xx >= 0) && (xx < 64);
            tpix[t] = min(max(yy, 0), 63) * 64 + min(max(xx, 0), 63);
        }
    }

    const float* xb  = x + (size_t)b * CIN * HW;
    const float* omb = om + (size_t)b * 54 * HW + pix;   // unused for CG==0
    __syncthreads();

    f32x4 acc[4][NT];
#pragma unroll
    for (int mt = 0; mt < 4; ++mt)
#pragma unroll
        for (int nt = 0; nt < NT; ++nt)
            acc[mt][nt] = (f32x4){0.f, 0.f, 0.f, 0.f};

    // deform tap state (carried across compile-time element sequence)
    float tw0 = 0.f, tw1 = 0.f, tw2 = 0.f, tw3 = 0.f, twsum = 0.f;
    int   ibase = 0, idx = 0, idy = 0;

#pragma unroll
    for (int ch = 0; ch < NCH; ++ch) {
        // ---- produce this thread's 32 A-row values (4 x ds_write_b128)
#pragma unroll
        for (int q = 0; q < 4; ++q) {
            f16x8 pk;
#pragma unroll
            for (int jj = 0; jj < 8; ++jj) {
                const int j  = q * 8 + jj;
                const int kk = ch * 32 + j;
                float v = 0.f;
                if (kk < KK) {
                    if (CG == 0) {
                        const int ci = kk / 9, t = kk - (kk / 9) * 9;
                        const float xval = xb[(size_t)ci * HW + tpix[t]];
                        v = tok[t] ? fmaf(lsa[ci], xval, lsc[ci]) : 0.f;
                    } else {
                        const int tp = kk / CG;          // g*9 + k
                        const int c  = kk - tp * CG;
                        const int g  = tp / 9, k = tp - (tp / 9) * 9;
                        if (c == 0) {
                            const float offy = omb[(size_t)tp * HW];
                            const float offx = omb[(size_t)(18 + tp) * HW];
                            const float mraw = omb[(size_t)(36 + tp) * HW];
                            const float msk  = 1.f / (1.f + __expf(-mraw));
                            const float py = (float)(h + k / 3 - 1) + offy;
                            const float px = (float)(ww + k % 3 - 1) + offx;
                            const float y0f = floorf(py), x0f = floorf(px);
                            const float lyf = py - y0f, lxf = px - x0f;
                            const int y0 = (int)y0f, x0 = (int)x0f;
                            const int y1 = y0 + 1,  x1 = x0 + 1;
                            const bool y0ok = (y0 >= 0) && (y0 < 64);
                            const bool y1ok = (y1 >= 0) && (y1 < 64);
                            const bool x0ok = (x0 >= 0) && (x0 < 64);
                            const bool x1ok = (x1 >= 0) && (x1 < 64);
                            tw0 = (1.f-lyf)*(1.f-lxf)*msk; if (!(y0ok&&x0ok)) tw0 = 0.f;
                            tw1 = (1.f-lyf)*lxf      *msk; if (!(y0ok&&x1ok)) tw1 = 0.f;
                            tw2 = lyf*(1.f-lxf)      *msk; if (!(y1ok&&x0ok)) tw2 = 0.f;
                            tw3 = lyf*lxf            *msk; if (!(y1ok&&x1ok)) tw3 = 0.f;
                            twsum = tw0 + tw1 + tw2 + tw3;
                            ibase = min(max(y0,0),63) * 64 + min(max(x0,0),63);
                            idx   = (min(max(x1,0),63) - min(max(x0,0),63));
                            idy   = (min(max(y1,0),63) - min(max(y0,0),63)) * 64;
                        }
                        const int chn = g * CG + c;
                        const float* xp = xb + (size_t)chn * HW + ibase;
                        const f32x2 r0 = *(const f32x2*)xp;          // [x0, x0+1]
                        const f32x2 r1 = *(const f32x2*)(xp + idy);  // @y1
                        const float v00 = r0.x, v01 = idx ? r0.y : r0.x;
                        const float v10 = r1.x, v11 = idx ? r1.y : r1.x;
                        const float gath = tw0*v00 + tw1*v01 + tw2*v10 + tw3*v11;
                        v = fmaf(lsa[chn], gath, lsc[chn] * twsum);
                    }
                }
                pk[jj] = (_Float16)v;
            }
            *(f16x8*)&vlds[(size_t)tid * 36 + q * 8] = pk;
        }
        __syncthreads();

        // ---- MFMA: A from LDS, B from precomputed fragments
        f16x8 bf[NT];
#pragma unroll
        for (int nt = 0; nt < NT; ++nt)
            bf[nt] = *(const f16x8*)&wf[((size_t)(ch * NT + nt) * 64 + lane) * 8];
#pragma unroll
        for (int mt = 0; mt < 4; ++mt) {
            const int p = wv * 64 + mt * 16 + (lane & 15);
            const f16x8 af = *(const f16x8*)&vlds[(size_t)p * 36 + (lane >> 4) * 8];
#pragma unroll
            for (int nt = 0; nt < NT; ++nt)
                acc[mt][nt] = __builtin_amdgcn_mfma_f32_16x16x32_f16(
                    af, bf[nt], acc[mt][nt], 0, 0, 0);
        }
        __syncthreads();
    }

    // ---- epilogue: LDS transpose (tlds overlays vlds; K-loop's final barrier
    //      already separates last MFMA read from first tlds write)
    const int pix0 = blockIdx.x * 256;
    float* obase = out + (size_t)b * O * HW + pix0;
#pragma unroll
    for (int nt = 0; nt < NT; ++nt) {
#pragma unroll
        for (int mt = 0; mt < 4; ++mt)
#pragma unroll
            for (int r = 0; r < 4; ++r)
                tlds[(size_t)(wv * 64 + mt * 16 + ((lane >> 4) << 2) + r) * 18 +
                     (lane & 15)] = acc[mt][nt][r];
        __syncthreads();

        float res[16];
#pragma unroll
        for (int oi = 0; oi < 16; ++oi) {
            const int o = nt * 16 + oi;
            float v = 0.f;
            if (o < O) {
                v = tlds[(size_t)tid * 18 + oi] + bias[o];
                if (RELU) v = fmaxf(v, 0.f);
                obase[(size_t)o * HW + tid] = v;
            }
            res[oi] = v;
        }
        if (STATS) {
            if (tid < 32) ls[tid] = 0.f;
            __syncthreads();
#pragma unroll
            for (int oi = 0; oi < 16; ++oi) {
                if (nt * 16 + oi < O) {
                    float s = res[oi], s2 = res[oi] * res[oi];
                    for (int off = 32; off; off >>= 1) {
                        s  += __shfl_down(s,  off);
                        s2 += __shfl_down(s2, off);
                    }
                    if ((tid & 63) == 0) {
                        atomicAdd(&ls[2 * oi],     s);
                        atomicAdd(&ls[2 * oi + 1], s2);
                    }
                }
            }
            __syncthreads();
            if (tid < 32 && (nt * 16 + (tid >> 1)) < O)
                atomicAdd(&sacc[nt * 32 + tid], ls[tid]);
        }
        __syncthreads();
    }
}

// ---------------------------------------------------------------------------
// BN apply in place on em (NCHW 64ch): 4,194,304 float4 -> 16384 blocks.
// ---------------------------------------------------------------------------
__global__ __launch_bounds__(256) void bn_apply4_k(
    float* __restrict__ y, const float* __restrict__ st,
    const float* __restrict__ gg, const float* __restrict__ bb)
{
    const size_t i4 = (size_t)blockIdx.x * 256 + threadIdx.x;
    const int c = (int)((i4 >> 10) & 63);
    const float m = st[c], r = st[64 + c];
    const float a = gg[c] * r, cc = bb[c] - gg[c] * m * r;
    float4 v = ((float4*)y)[i4];
    v.x = a*v.x + cc; v.y = a*v.y + cc; v.z = a*v.z + cc; v.w = a*v.w + cc;
    ((float4*)y)[i4] = v;
}

__global__ __launch_bounds__(256) void pool_k(
    const float* __restrict__ em, float* __restrict__ pooled)
{
    const int b = blockIdx.x, c = blockIdx.y, t = threadIdx.x;
    const int q = t >> 6, l = t & 63;
    const float* p = em + ((size_t)b * 64 + c) * HW + (q >> 1) * 32 * W_ + (q & 1) * 32;
    float s = 0.f;
    for (int i = l; i < 1024; i += 64) {
        const int yy = i >> 5, xx = i & 31;
        s += p[yy * W_ + xx];
    }
    for (int off = 32; off; off >>= 1) s += __shfl_down(s, off);
    if (l == 0) pooled[b * 256 + c * 4 + q] = s * (1.f / 1024.f);
}

__global__ __launch_bounds__(64) void fc_k(
    const float* __restrict__ pooled, const float* __restrict__ fcw,
    const float* __restrict__ fcb, float* __restrict__ out)
{
    const int b = blockIdx.x, t = threadIdx.x;
    __shared__ float logits[10];
    if (t < 10) {
        float l = fcb[t];
        const float* p = pooled + b * 256;
        for (int j = 0; j < 256; ++j) l += fcw[t * 256 + j] * p[j];
        logits[t] = l;
    }
    __syncthreads();
    if (t == 0) {
        float mx = logits[0];
        for (int i = 1; i < 10; ++i) mx = fmaxf(mx, logits[i]);
        float e[10]; float sum = 0.f;
        for (int i = 0; i < 10; ++i) { e[i] = __expf(logits[i] - mx); sum += e[i]; }
        const float inv = 1.f / sum;
        for (int i = 0; i < 10; ++i) out[b * 10 + i] = e[i] * inv;
    }
}

// ---------------------------------------------------------------------------
extern "C" void kernel_launch(void* const* d_in, const int* in_sizes, int n_in,
                              void* d_out, int out_size, void* d_ws, size_t ws_size,
                              hipStream_t stream)
{
    const float* x       = (const float*)d_in[0];
    const float* conv1_w = (const float*)d_in[1];
    const float* bn1_g   = (const float*)d_in[2];
    const float* bn1_b   = (const float*)d_in[3];
    const float* conv2_w = (const float*)d_in[4];
    const float* conv2_b = (const float*)d_in[5];
    const float* bn2_g   = (const float*)d_in[6];
    const float* bn2_b   = (const float*)d_in[7];
    const float* off1_w  = (const float*)d_in[8];
    const float* off1_b  = (const float*)d_in[9];
    const float* d1_w    = (const float*)d_in[10];
    const float* d1_b    = (const float*)d_in[11];
    const float* bn3_g   = (const float*)d_in[12];
    const float* bn3_b   = (const float*)d_in[13];
    const float* off2_w  = (const float*)d_in[14];
    const float* off2_b  = (const float*)d_in[15];
    const float* d2_w    = (const float*)d_in[16];
    const float* d2_b    = (const float*)d_in[17];
    const float* bn4_g   = (const float*)d_in[18];
    const float* bn4_b   = (const float*)d_in[19];
    const float* fc_w    = (const float*)d_in[20];
    const float* fc_b    = (const float*)d_in[21];

    // Workspace (floats), all NCHW. ~119.7 MB.
    float* ws = (float*)d_ws;
    float* Bb = ws;                    // [B][20][HW]  5,242,880
    float* D  = ws + 5242880;          // [B][40][HW] 10,485,760
    float* C  = ws + 15728640;         // om [B][54][HW] 14,155,776
    float* A  = C;                     // [B][8][HW] (aliases C; dead before off1)
    float* sm = ws + 29884416;
    float* s1 = sm,        *s2 = sm + 16,  *s3 = sm + 56,  *s4 = sm + 136; // sums (264)
    float* st1 = sm + 264, *st2 = sm + 280, *st3 = sm + 320, *st4 = sm + 400;
    float* pooled = sm + 528;          // 16384 (end 16912)
    // MFMA weight fragments (f16)
    _Float16* c2F = (_Float16*)(sm + 16912);  //  3,072 f16
    _Float16* o1F = (_Float16*)(sm + 18448);  // 12,288 f16
    _Float16* o2F = (_Float16*)(sm + 24592);  // 24,576 f16
    _Float16* d1F = (_Float16*)(sm + 36880);  //  9,216 f16
    _Float16* d2F = (_Float16*)(sm + 41488);  // 24,576 f16 (end 53776)

    float* outp = (float*)d_out;
    float* em   = outp + 640;          // NCHW [64][64][64][64]

    const dim3 blk(256);
    const dim3 gpix(16, B_);

    (void)hipMemsetAsync(sm, 0, 264 * sizeof(float), stream);

    // pack weights into fragment layout:        w        dst   O   KK  NT NCH CG
    wfrag_k<<<(3072  + 255)/256, blk, 0, stream>>>(conv2_w, c2F, 20,  72, 2,  3,  0);
    wfrag_k<<<(12288 + 255)/256, blk, 0, stream>>>(off1_w,  o1F, 54, 180, 4,  6,  0);
    wfrag_k<<<(24576 + 255)/256, blk, 0, stream>>>(off2_w,  o2F, 54, 360, 4, 12,  0);
    wfrag_k<<<(9216  + 255)/256, blk, 0, stream>>>(d1_w,    d1F, 40, 180, 3,  6, 10);
    wfrag_k<<<(24576 + 255)/256, blk, 0, stream>>>(d2_w,    d2F, 64, 360, 4, 12, 20);

    // layer 1: conv(3->8)+relu -> A + stats1
    conv1_k<<<gpix, blk, 0, stream>>>(x, conv1_w, A, s1);
    bn_fin_k<8><<<1, 64, 0, stream>>>(s1, st1);

    // layer 2: conv(8->20)+bias+relu (BN1 inline) -> Bb + stats2
    mfconv_k<72, 20, 2, 0, 8, true, true><<<gpix, blk, 0, stream>>>(
        A, nullptr, c2F, conv2_b, st1, bn1_g, bn1_b, Bb, s2);
    bn_fin_k<20><<<1, 64, 0, stream>>>(s2, st2);

    // deform block 1: off-conv(20->54, BN2 inline) -> C; deform(20->40) -> D
    mfconv_k<180, 54, 4, 0, 20, false, false><<<gpix, blk, 0, stream>>>(
        Bb, nullptr, o1F, off1_b, st2, bn2_g, bn2_b, C, nullptr);
    mfconv_k<180, 40, 3, 10, 20, true, true><<<gpix, blk, 0, stream>>>(
        Bb, C, d1F, d1_b, st2, bn2_g, bn2_b, D, s3);
    bn_fin_k<40><<<1, 64, 0, stream>>>(s3, st3);

    // deform block 2: off-conv(40->54, BN3 inline) -> C; deform(40->64) -> em
    mfconv_k<360, 54, 4, 0, 40, false, false><<<gpix, blk, 0, stream>>>(
        D, nullptr, o2F, off2_b, st3, bn3_g, bn3_b, C, nullptr);
    mfconv_k<360, 64, 4, 20, 40, true, true><<<gpix, blk, 0, stream>>>(
        D, C, d2F, d2_b, st3, bn3_g, bn3_b, em, s4);
    bn_fin_k<64><<<1, 64, 0, stream>>>(s4, st4);

    // layer-4 BN in place on em
    bn_apply4_k<<<16384, blk, 0, stream>>>(em, st4, bn4_g, bn4_b);

    // head
    pool_k<<<dim3(B_, 64), blk, 0, stream>>>(em, pooled);
    fc_k<<<B_, 64, 0, stream>>>(pooled, fc_w, fc_b, outp);
}